// Round 9
// baseline (370.241 us; speedup 1.0000x reference)
//
#include <hip/hip_runtime.h>

// Centroids: argmin_c ||latent[r] - coords[c]||^2, 131072 rows x 2048 coords, D=128.
//
// R9: pure-integer argmax epilogue. R8 counters: VALUBusy 58% / MfmaUtil 27% ->
//   VALU-issue-bound (~28 VALU/score). Fix: GLOBAL quant scales (qA for all
//   latent, qB for all coords, amax via prep_amax kernel) make
//   S = 128*I1 + I2 + V_c an int32 comparable across coords:
//     V_c = rint(-64*c2_c/(qA*qB)) injected FREE via I2-acc init {v,v,v,v}.
//   Epilogue/score: lshl_add,cmp,cndmask,max,min,max = 6 int ops (was 9 float,
//   no cvt/mul/fma/qc-load/qAr-shfl). NCH=64 (R7 staging) + 16-row waves
//   (R8 geometry: VGPR<=64 slot -> 4 waves/SIMD, grid 2048).
//   Margin test in ints: b1-b2 < 1.28/sAB (== 0.01 half-scale value units,
//   ~14-sigma over the ~7e-4 err std). i8 hi/lo 3-pass MFMA unchanged.
// Kept (validated): gl_lds w=16 dbuf + counted vmcnt(4), de-phase entry sleep,
//   setprio(1) around MFMA, no-tiebreak butterfly, fp64 refine margin net.
//
// ws layout (bytes): 0 amax (2 u32, memsetAsync-zeroed) | 16384 counter |
//   32768 worklist (128KB) | 196608 V (8KB int) | 262144 Bh (256KB) |
//   524288 Bl (256KB) | end 786432

constexpr int D = 128;
constexpr int C = 2048;
constexpr int NCH = 64;            // coords per chunk
constexpr int NCHUNKS = C / NCH;   // 32
constexpr int WL_CAP = 32768;

constexpr size_t WS_CNT = 16384;
constexpr size_t WS_WL  = 32768;
constexpr size_t WS_V   = 196608;
constexpr size_t WS_BH  = 262144;
constexpr size_t WS_BL  = 524288;

typedef __attribute__((ext_vector_type(4))) int i32x4;
typedef unsigned int u32;

__device__ __forceinline__ int pack4(int a0, int a1, int a2, int a3) {
    return (int)(((u32)a0 & 255u) | (((u32)a1 & 255u) << 8) |
                 (((u32)a2 & 255u) << 16) | (((u32)a3 & 255u) << 24));
}

// quantize v -> hi (|h|<=127), lo (|l|<=64): v = h*qa + l*qa/128 + eps
__device__ __forceinline__ void q2(float v, float qa, float inv, float inv128,
                                   int* h, int* l) {
    float hf = __builtin_rintf(v * inv);
    *h = (int)hf;
    float r = fmaf(-hf, qa, v);
    *l = (int)__builtin_rintf(r * inv128);
}

// async global->LDS, 16B per lane (wave-uniform base + lane*16: contiguous).
__device__ __forceinline__ void gl_lds16(const void* g, void* l) {
    __builtin_amdgcn_global_load_lds(
        (const __attribute__((address_space(1))) u32*)g,
        (__attribute__((address_space(3))) u32*)l, 16, 0, 0);
}

// ---------------- prep1: global amax of |latent|, |coords| ----------------
__global__ void prep_amax(const float* __restrict__ latent, int nA4,
                          const float* __restrict__ coords, int nB4,
                          unsigned* __restrict__ amax, int* __restrict__ counter) {
    int t = blockIdx.x * blockDim.x + threadIdx.x;
    if (t == 0) *counter = 0;
    int stride = gridDim.x * blockDim.x;
    float mA = 0.f, mB = 0.f;
    for (int i = t; i < nA4; i += stride) {
        float4 v = ((const float4*)latent)[i];
        mA = fmaxf(mA, fmaxf(fmaxf(fabsf(v.x), fabsf(v.y)),
                             fmaxf(fabsf(v.z), fabsf(v.w))));
    }
    for (int i = t; i < nB4; i += stride) {
        float4 v = ((const float4*)coords)[i];
        mB = fmaxf(mB, fmaxf(fmaxf(fabsf(v.x), fabsf(v.y)),
                             fmaxf(fabsf(v.z), fabsf(v.w))));
    }
#pragma unroll
    for (int m = 1; m <= 32; m <<= 1) {
        mA = fmaxf(mA, __shfl_xor(mA, m, 64));
        mB = fmaxf(mB, __shfl_xor(mB, m, 64));
    }
    if ((threadIdx.x & 63) == 0) {   // positive floats: uint order == float order
        atomicMax(amax + 0, __float_as_uint(mA));
        atomicMax(amax + 1, __float_as_uint(mB));
    }
}

// ---------------- prep2: int8 B images (global qB) + V table ----------------
// 4 threads/coord; part p handles elems p*32..p*32+31 (granules g8 = 2p,2p+1).
// Image: coord row c*128B, granule pos = g8 ^ (c&7) (matches read swizzle).
__global__ void prep_coords(const float* __restrict__ coords,
                            const unsigned* __restrict__ amax,
                            signed char* __restrict__ Bh,
                            signed char* __restrict__ Bl,
                            int* __restrict__ Vt) {
    int t = blockIdx.x * blockDim.x + threadIdx.x;
    if (t >= C * 4) return;
    int c = t >> 2, p = t & 3;
    float aA = fmaxf(__uint_as_float(amax[0]), 1e-30f);
    float aB = fmaxf(__uint_as_float(amax[1]), 1e-30f);
    float qb = aB * (1.f / 127.f);
    float inv = 127.f / aB;
    float inv128 = inv * 128.f;

    float v[32];
#pragma unroll
    for (int i = 0; i < 8; ++i)
        *(float4*)(v + i * 4) = *(const float4*)(coords + (size_t)c * D + p * 32 + i * 4);
    float ss = 0.f;
#pragma unroll
    for (int j = 0; j < 32; ++j) ss = fmaf(v[j], v[j], ss);
#pragma unroll
    for (int m = 1; m <= 2; m <<= 1) ss += __shfl_xor(ss, m, 64);

#pragma unroll
    for (int g = 0; g < 2; ++g) {        // two 16-elem granules
        int g8 = p * 2 + g;
        int hw[4], lw[4];
#pragma unroll
        for (int w = 0; w < 4; ++w) {
            int h0, l0, h1, l1, h2, l2, h3, l3;
            q2(v[g * 16 + w * 4 + 0], qb, inv, inv128, &h0, &l0);
            q2(v[g * 16 + w * 4 + 1], qb, inv, inv128, &h1, &l1);
            q2(v[g * 16 + w * 4 + 2], qb, inv, inv128, &h2, &l2);
            q2(v[g * 16 + w * 4 + 3], qb, inv, inv128, &h3, &l3);
            hw[w] = pack4(h0, h1, h2, h3);
            lw[w] = pack4(l0, l1, l2, l3);
        }
        size_t off = (size_t)c * 128 + (size_t)((g8 ^ (c & 7)) * 16);
        *(i32x4*)(Bh + off) = (i32x4){hw[0], hw[1], hw[2], hw[3]};
        *(i32x4*)(Bl + off) = (i32x4){lw[0], lw[1], lw[2], lw[3]};
    }
    if (p == 0) {
        float sAB = aA * aB * (1.f / 16129.f);   // qA*qB
        Vt[c] = (int)rintf(-64.f * ss / sAB);    // -c2/2 in I2-units (qA*qB/128)
    }
}

// ---------------- main kernel ----------------

__global__ __launch_bounds__(256, 4) void centroid_fast(
        const float* __restrict__ latent,
        const signed char* __restrict__ Bh_img,
        const signed char* __restrict__ Bl_img,
        const int* __restrict__ Vg,
        const unsigned* __restrict__ amax,
        int* __restrict__ out,
        int* __restrict__ counter,
        int* __restrict__ worklist) {
    // dbuf 2x8KB hi + 2x8KB lo + V 8KB = 40 KB -> 4 blocks/CU (w/ VGPR<=64)
    __shared__ __align__(16) signed char Bh[2][NCH * 128], Bl[2][NCH * 128];
    __shared__ __align__(16) int Vs[C];

    const int tid  = threadIdx.x;
    const int wid  = tid >> 6;            // wave 0..3 -> rows wid*16..wid*16+15
    const int lane = tid & 63;
    const int q    = lane >> 4, lr = lane & 15;
    const int row_block = blockIdx.x * 64;

    // de-phase co-resident blocks (validated R3): 4 phases
    {
        int ph = (blockIdx.x ^ (blockIdx.x >> 8)) & 3;
        for (int i = 0; i < ph * 2; ++i) __builtin_amdgcn_s_sleep(8);
    }

    // ---- prologue: stage chunk 0 (4 gl_lds) + V table (2 gl_lds) ----
#pragma unroll
    for (int i = 0; i < 2; ++i) {
        int e = (i * 256 + tid) * 16;
        gl_lds16(Bh_img + e, &Bh[0][e]);
        gl_lds16(Bl_img + e, &Bl[0][e]);
    }
#pragma unroll
    for (int i = 0; i < 2; ++i) {
        int off = (i * 256 + tid) * 16;
        gl_lds16((const char*)Vg + off, (char*)Vs + off);
    }

    // global scales
    const float aA = fmaxf(__uint_as_float(amax[0]), 1e-30f);
    const float aB = fmaxf(__uint_as_float(amax[1]), 1e-30f);
    const float sAB = aA * aB * (1.f / 16129.f);     // qA*qB
    const int M_int = (int)(1.28f / sAB) + 1;        // margin 0.01 in I2-units

    // ---- A fragments: int8 hi/lo with GLOBAL qA. Lane holds row wid*16+lr,
    // k = ks*64 + q*16 + 0..15 -> i32x4 per ks. 16 VGPRs, no qAr broadcast.
    i32x4 Ah[2], Al[2];
    {
        const float* rp = latent + (size_t)(row_block + wid * 16 + lr) * D;
        float qa = aA * (1.f / 127.f);
        float inv = 127.f / aA;
        float inv128 = inv * 128.f;
#pragma unroll
        for (int ks = 0; ks < 2; ++ks) {
            float v[16];
#pragma unroll
            for (int i = 0; i < 4; ++i)
                *(float4*)(v + i * 4) = *(const float4*)(rp + ks * 64 + q * 16 + i * 4);
            int hw[4], lw[4];
#pragma unroll
            for (int w = 0; w < 4; ++w) {
                int h0, l0, h1, l1, h2, l2, h3, l3;
                q2(v[w * 4 + 0], qa, inv, inv128, &h0, &l0);
                q2(v[w * 4 + 1], qa, inv, inv128, &h1, &l1);
                q2(v[w * 4 + 2], qa, inv, inv128, &h2, &l2);
                q2(v[w * 4 + 3], qa, inv, inv128, &h3, &l3);
                hw[w] = pack4(h0, h1, h2, h3);
                lw[w] = pack4(l0, l1, l2, l3);
            }
            Ah[ks] = (i32x4){hw[0], hw[1], hw[2], hw[3]};
            Al[ks] = (i32x4){lw[0], lw[1], lw[2], lw[3]};
        }
    }

    // int argmax state over S = 128*I1 + I2 + V (== argmin distance), 4 slots
    int b1[4], b2[4], bidx[4];
#pragma unroll
    for (int s = 0; s < 4; ++s) {
        b1[s] = -2147483647 - 1; b2[s] = -2147483647 - 1; bidx[s] = 0;
    }

    __syncthreads();   // full drain: chunk-0 + V stage + A loads visible

    for (int ch = 0; ch < NCHUNKS; ++ch) {
        const int buf = ch & 1;
        const int chbase = ch * NCH;
        // issue next chunk's stage FIRST, then counted wait on current's 4
        if (ch + 1 < NCHUNKS) {
            const signed char* sh = Bh_img + (size_t)(ch + 1) * (NCH * 128);
            const signed char* sl = Bl_img + (size_t)(ch + 1) * (NCH * 128);
#pragma unroll
            for (int i = 0; i < 2; ++i) {
                int e = (i * 256 + tid) * 16;
                gl_lds16(sh + e, &Bh[buf ^ 1][e]);
                gl_lds16(sl + e, &Bl[buf ^ 1][e]);
            }
            asm volatile("s_waitcnt vmcnt(4)" ::: "memory");
        } else {
            asm volatile("s_waitcnt vmcnt(0)" ::: "memory");
        }
        __builtin_amdgcn_s_barrier();

#pragma unroll
        for (int nt = 0; nt < 4; ++nt) {
            const int nl = nt * 16 + lr;
            const int v0 = Vs[chbase + nl];       // -c2/2 in I2-units
            i32x4 I1 = (i32x4){0, 0, 0, 0};
            i32x4 I2 = (i32x4){v0, v0, v0, v0};   // c2 folded into acc init: free
            __builtin_amdgcn_s_setprio(1);
#pragma unroll
            for (int ks = 0; ks < 2; ++ks) {
                const int e = nl * 128 + (((ks << 2) | q) ^ (lr & 7)) * 16;
                i32x4 bh = *(const i32x4*)(&Bh[buf][e]);
                i32x4 bl = *(const i32x4*)(&Bl[buf][e]);
                I1 = __builtin_amdgcn_mfma_i32_16x16x64_i8(Ah[ks], bh, I1, 0, 0, 0);
                I2 = __builtin_amdgcn_mfma_i32_16x16x64_i8(Ah[ks], bl, I2, 0, 0, 0);
                I2 = __builtin_amdgcn_mfma_i32_16x16x64_i8(Al[ks], bh, I2, 0, 0, 0);
            }
            __builtin_amdgcn_s_setprio(0);
            const int n_global = chbase + nl;
            // pure-int epilogue: 6 VALU/score
#pragma unroll
            for (int r = 0; r < 4; ++r) {
                int S = (int)(((u32)I1[r] << 7) + (u32)I2[r]);
                bool gt = S > b1[r];
                b2[r]   = max(b2[r], min(S, b1[r]));
                b1[r]   = max(S, b1[r]);
                bidx[r] = gt ? n_global : bidx[r];
            }
        }
        __builtin_amdgcn_s_barrier();   // all reads of buf done before restage
    }

    // butterfly over the 16 col-residue lanes (int max semantics, no tie-break:
    // ties -> gap 0 < margin -> exact refine resolves)
#pragma unroll
    for (int m = 1; m <= 8; m <<= 1) {
#pragma unroll
        for (int s = 0; s < 4; ++s) {
            int oa = __shfl_xor(b1[s], m, 64);
            int ob = __shfl_xor(b2[s], m, 64);
            int oi = __shfl_xor(bidx[s], m, 64);
            int mn = min(b1[s], oa);
            b2[s] = max(max(b2[s], ob), mn);
            bool take = oa > b1[s];
            b1[s]   = take ? oa : b1[s];
            bidx[s] = take ? oi : bidx[s];
        }
    }
    // slot s canonical in lane lr==s; row = wid*16 + q*4 + s
#pragma unroll
    for (int s = 0; s < 4; ++s) {
        if (lr == s) {
            int row = row_block + wid * 16 + q * 4 + s;
            out[row] = bidx[s];
            if (b1[s] - b2[s] < M_int) {
                int w = atomicAdd(counter, 1);
                if (w < WL_CAP) worklist[w] = row;
            }
        }
    }
}

// ---------------- fp64 refine (1024 threads, 2 coords/thread) ----------------

__global__ __launch_bounds__(1024) void refine_fp64(
        const float* __restrict__ latent, const float* __restrict__ coords,
        const int* __restrict__ worklist, const int* __restrict__ counter,
        int wl_cap, int* __restrict__ out) {
    __shared__ float  xs[D];
    __shared__ double rv[1024];
    __shared__ int    ri[1024];

    int n = *counter;
    if (n > wl_cap) n = wl_cap;

    for (int wi = blockIdx.x; wi < n; wi += gridDim.x) {
        int row = worklist[wi];
        if (threadIdx.x < D)
            xs[threadIdx.x] = latent[(size_t)row * D + threadIdx.x];
        __syncthreads();

        double best = 1.0e300;
        int    bix  = 0;
        for (int c = threadIdx.x; c < C; c += 1024) {
            const float4* cp = (const float4*)(coords + (size_t)c * D);
            double s0 = 0.0, s1 = 0.0, s2 = 0.0, s3 = 0.0;
#pragma unroll 8
            for (int k4 = 0; k4 < 32; ++k4) {
                float4 v = cp[k4];
                double d0 = (double)xs[k4 * 4 + 0] - (double)v.x;
                double d1 = (double)xs[k4 * 4 + 1] - (double)v.y;
                double d2 = (double)xs[k4 * 4 + 2] - (double)v.z;
                double d3 = (double)xs[k4 * 4 + 3] - (double)v.w;
                s0 = fma(d0, d0, s0); s1 = fma(d1, d1, s1);
                s2 = fma(d2, d2, s2); s3 = fma(d3, d3, s3);
            }
            double s = (s0 + s1) + (s2 + s3);
            if (s < best) { best = s; bix = c; }
        }
        rv[threadIdx.x] = best;
        ri[threadIdx.x] = bix;
        __syncthreads();
        for (int off = 512; off > 0; off >>= 1) {
            if (threadIdx.x < off) {
                double ov = rv[threadIdx.x + off];
                int    oi = ri[threadIdx.x + off];
                if (ov < rv[threadIdx.x] ||
                    (ov == rv[threadIdx.x] && oi < ri[threadIdx.x])) {
                    rv[threadIdx.x] = ov;
                    ri[threadIdx.x] = oi;
                }
            }
            __syncthreads();
        }
        if (threadIdx.x == 0) out[row] = ri[0];
        __syncthreads();
    }
}

extern "C" void kernel_launch(void* const* d_in, const int* in_sizes, int n_in,
                              void* d_out, int out_size, void* d_ws, size_t ws_size,
                              hipStream_t stream) {
    const float* latent = (const float*)d_in[0];
    const float* coords = (const float*)d_in[1];
    int*         out    = (int*)d_out;

    char* ws = (char*)d_ws;
    unsigned* amax  = (unsigned*)ws;
    int*    counter = (int*)(ws + WS_CNT);
    int*    wl      = (int*)(ws + WS_WL);
    int*    Vt      = (int*)(ws + WS_V);
    signed char* Bh = (signed char*)(ws + WS_BH);
    signed char* Bl = (signed char*)(ws + WS_BL);
    const int n_rows = in_sizes[0] / D;   // 131072
    const int nA4 = n_rows * D / 4;
    const int nB4 = C * D / 4;

    hipMemsetAsync(d_ws, 0, 16, stream);  // zero amax slots (stream-ordered)
    prep_amax<<<1024, 256, 0, stream>>>(latent, nA4, coords, nB4, amax, counter);
    prep_coords<<<(C * 4) / 256, 256, 0, stream>>>(coords, amax, Bh, Bl, Vt);
    centroid_fast<<<n_rows / 64, 256, 0, stream>>>(latent, Bh, Bl, Vt, amax, out,
                                                   counter, wl);
    refine_fp64<<<608, 1024, 0, stream>>>(latent, coords, wl, counter, WL_CAP, out);
}

// Round 10
// 285.057 us; speedup vs baseline: 1.2988x; 1.2988x over previous
//
#include <hip/hip_runtime.h>

// Centroids: argmin_c ||latent[r] - coords[c]||^2, 131072 rows x 2048 coords, D=128.
//
// R9 (validated): pure-integer argmax epilogue. GLOBAL quant scales (qA latent,
//   qB coords) make S = 128*I1 + I2 + V_c int32-comparable per row:
//     V_c = rint(-64*c2_c/(qA*qB)) injected free via I2-acc init.
//   i8 hi/lo 3-pass MFMA (mfma_i32_16x16x64_i8); 16-row waves, NCH=64,
//   VGPR 52 -> 64-slot -> 4 waves/SIMD (occ 37%). centroid 137 us.
// R10 FIX: prep_amax had 4096 waves x 2 device-scope atomicMax to the SAME two
//   dwords (~100 us serialization at the cross-XCD coherence point) -> headline
//   regression R8 280 -> R9 370 despite faster centroid. v2: per-block LDS
//   reduction -> 2 atomics/block x 256 blocks = 512 total (~5 us), grid 256.
//   Everything else byte-identical to R9 to isolate the fix.
// Kept (validated): gl_lds w=16 dbuf + counted vmcnt(4), de-phase entry sleep,
//   setprio(1) around MFMA, no-tiebreak butterfly, int margin test
//   b1-b2 < 1.28/sAB (= 0.01 half-scale, ~7-sigma), fp64 refine margin net.
//
// ws layout (bytes): 0 amax (2 u32, memsetAsync-zeroed) | 16384 counter |
//   32768 worklist (128KB) | 196608 V (8KB int) | 262144 Bh (256KB) |
//   524288 Bl (256KB) | end 786432

constexpr int D = 128;
constexpr int C = 2048;
constexpr int NCH = 64;            // coords per chunk
constexpr int NCHUNKS = C / NCH;   // 32
constexpr int WL_CAP = 32768;

constexpr size_t WS_CNT = 16384;
constexpr size_t WS_WL  = 32768;
constexpr size_t WS_V   = 196608;
constexpr size_t WS_BH  = 262144;
constexpr size_t WS_BL  = 524288;

typedef __attribute__((ext_vector_type(4))) int i32x4;
typedef unsigned int u32;

__device__ __forceinline__ int pack4(int a0, int a1, int a2, int a3) {
    return (int)(((u32)a0 & 255u) | (((u32)a1 & 255u) << 8) |
                 (((u32)a2 & 255u) << 16) | (((u32)a3 & 255u) << 24));
}

// quantize v -> hi (|h|<=127), lo (|l|<=64): v = h*qa + l*qa/128 + eps
__device__ __forceinline__ void q2(float v, float qa, float inv, float inv128,
                                   int* h, int* l) {
    float hf = __builtin_rintf(v * inv);
    *h = (int)hf;
    float r = fmaf(-hf, qa, v);
    *l = (int)__builtin_rintf(r * inv128);
}

// async global->LDS, 16B per lane (wave-uniform base + lane*16: contiguous).
__device__ __forceinline__ void gl_lds16(const void* g, void* l) {
    __builtin_amdgcn_global_load_lds(
        (const __attribute__((address_space(1))) u32*)g,
        (__attribute__((address_space(3))) u32*)l, 16, 0, 0);
}

// ---------------- prep1: global amax of |latent|, |coords| ----------------
// v2: per-block LDS reduce -> 2 atomics per block (R9 had 2 per WAVE: ~100us
// of cross-XCD serialization on two dwords). Grid 256 saturates HBM for the scan.
__global__ __launch_bounds__(256) void prep_amax(
        const float* __restrict__ latent, int nA4,
        const float* __restrict__ coords, int nB4,
        unsigned* __restrict__ amax, int* __restrict__ counter) {
    __shared__ float sA[4], sB[4];
    int t = blockIdx.x * blockDim.x + threadIdx.x;
    if (t == 0) *counter = 0;
    int stride = gridDim.x * blockDim.x;
    float mA = 0.f, mB = 0.f;
    for (int i = t; i < nA4; i += stride) {
        float4 v = ((const float4*)latent)[i];
        mA = fmaxf(mA, fmaxf(fmaxf(fabsf(v.x), fabsf(v.y)),
                             fmaxf(fabsf(v.z), fabsf(v.w))));
    }
    for (int i = t; i < nB4; i += stride) {
        float4 v = ((const float4*)coords)[i];
        mB = fmaxf(mB, fmaxf(fmaxf(fabsf(v.x), fabsf(v.y)),
                             fmaxf(fabsf(v.z), fabsf(v.w))));
    }
#pragma unroll
    for (int m = 1; m <= 32; m <<= 1) {
        mA = fmaxf(mA, __shfl_xor(mA, m, 64));
        mB = fmaxf(mB, __shfl_xor(mB, m, 64));
    }
    int w = threadIdx.x >> 6;
    if ((threadIdx.x & 63) == 0) { sA[w] = mA; sB[w] = mB; }
    __syncthreads();
    if (threadIdx.x == 0) {   // positive floats: uint order == float order
        float a = fmaxf(fmaxf(sA[0], sA[1]), fmaxf(sA[2], sA[3]));
        float b = fmaxf(fmaxf(sB[0], sB[1]), fmaxf(sB[2], sB[3]));
        atomicMax(amax + 0, __float_as_uint(a));
        atomicMax(amax + 1, __float_as_uint(b));
    }
}

// ---------------- prep2: int8 B images (global qB) + V table ----------------
// 4 threads/coord; part p handles elems p*32..p*32+31 (granules g8 = 2p,2p+1).
// Image: coord row c*128B, granule pos = g8 ^ (c&7) (matches read swizzle).
__global__ void prep_coords(const float* __restrict__ coords,
                            const unsigned* __restrict__ amax,
                            signed char* __restrict__ Bh,
                            signed char* __restrict__ Bl,
                            int* __restrict__ Vt) {
    int t = blockIdx.x * blockDim.x + threadIdx.x;
    if (t >= C * 4) return;
    int c = t >> 2, p = t & 3;
    float aA = fmaxf(__uint_as_float(amax[0]), 1e-30f);
    float aB = fmaxf(__uint_as_float(amax[1]), 1e-30f);
    float qb = aB * (1.f / 127.f);
    float inv = 127.f / aB;
    float inv128 = inv * 128.f;

    float v[32];
#pragma unroll
    for (int i = 0; i < 8; ++i)
        *(float4*)(v + i * 4) = *(const float4*)(coords + (size_t)c * D + p * 32 + i * 4);
    float ss = 0.f;
#pragma unroll
    for (int j = 0; j < 32; ++j) ss = fmaf(v[j], v[j], ss);
#pragma unroll
    for (int m = 1; m <= 2; m <<= 1) ss += __shfl_xor(ss, m, 64);

#pragma unroll
    for (int g = 0; g < 2; ++g) {        // two 16-elem granules
        int g8 = p * 2 + g;
        int hw[4], lw[4];
#pragma unroll
        for (int w = 0; w < 4; ++w) {
            int h0, l0, h1, l1, h2, l2, h3, l3;
            q2(v[g * 16 + w * 4 + 0], qb, inv, inv128, &h0, &l0);
            q2(v[g * 16 + w * 4 + 1], qb, inv, inv128, &h1, &l1);
            q2(v[g * 16 + w * 4 + 2], qb, inv, inv128, &h2, &l2);
            q2(v[g * 16 + w * 4 + 3], qb, inv, inv128, &h3, &l3);
            hw[w] = pack4(h0, h1, h2, h3);
            lw[w] = pack4(l0, l1, l2, l3);
        }
        size_t off = (size_t)c * 128 + (size_t)((g8 ^ (c & 7)) * 16);
        *(i32x4*)(Bh + off) = (i32x4){hw[0], hw[1], hw[2], hw[3]};
        *(i32x4*)(Bl + off) = (i32x4){lw[0], lw[1], lw[2], lw[3]};
    }
    if (p == 0) {
        float sAB = aA * aB * (1.f / 16129.f);   // qA*qB
        Vt[c] = (int)rintf(-64.f * ss / sAB);    // -c2/2 in I2-units (qA*qB/128)
    }
}

// ---------------- main kernel ----------------

__global__ __launch_bounds__(256, 4) void centroid_fast(
        const float* __restrict__ latent,
        const signed char* __restrict__ Bh_img,
        const signed char* __restrict__ Bl_img,
        const int* __restrict__ Vg,
        const unsigned* __restrict__ amax,
        int* __restrict__ out,
        int* __restrict__ counter,
        int* __restrict__ worklist) {
    // dbuf 2x8KB hi + 2x8KB lo + V 8KB = 40 KB -> 4 blocks/CU (w/ VGPR<=64)
    __shared__ __align__(16) signed char Bh[2][NCH * 128], Bl[2][NCH * 128];
    __shared__ __align__(16) int Vs[C];

    const int tid  = threadIdx.x;
    const int wid  = tid >> 6;            // wave 0..3 -> rows wid*16..wid*16+15
    const int lane = tid & 63;
    const int q    = lane >> 4, lr = lane & 15;
    const int row_block = blockIdx.x * 64;

    // de-phase co-resident blocks (validated R3): 4 phases
    {
        int ph = (blockIdx.x ^ (blockIdx.x >> 8)) & 3;
        for (int i = 0; i < ph * 2; ++i) __builtin_amdgcn_s_sleep(8);
    }

    // ---- prologue: stage chunk 0 (4 gl_lds) + V table (2 gl_lds) ----
#pragma unroll
    for (int i = 0; i < 2; ++i) {
        int e = (i * 256 + tid) * 16;
        gl_lds16(Bh_img + e, &Bh[0][e]);
        gl_lds16(Bl_img + e, &Bl[0][e]);
    }
#pragma unroll
    for (int i = 0; i < 2; ++i) {
        int off = (i * 256 + tid) * 16;
        gl_lds16((const char*)Vg + off, (char*)Vs + off);
    }

    // global scales
    const float aA = fmaxf(__uint_as_float(amax[0]), 1e-30f);
    const float aB = fmaxf(__uint_as_float(amax[1]), 1e-30f);
    const float sAB = aA * aB * (1.f / 16129.f);     // qA*qB
    const int M_int = (int)(1.28f / sAB) + 1;        // margin 0.01 in I2-units

    // ---- A fragments: int8 hi/lo with GLOBAL qA. Lane holds row wid*16+lr,
    // k = ks*64 + q*16 + 0..15 -> i32x4 per ks. 16 VGPRs, no qAr broadcast.
    i32x4 Ah[2], Al[2];
    {
        const float* rp = latent + (size_t)(row_block + wid * 16 + lr) * D;
        float qa = aA * (1.f / 127.f);
        float inv = 127.f / aA;
        float inv128 = inv * 128.f;
#pragma unroll
        for (int ks = 0; ks < 2; ++ks) {
            float v[16];
#pragma unroll
            for (int i = 0; i < 4; ++i)
                *(float4*)(v + i * 4) = *(const float4*)(rp + ks * 64 + q * 16 + i * 4);
            int hw[4], lw[4];
#pragma unroll
            for (int w = 0; w < 4; ++w) {
                int h0, l0, h1, l1, h2, l2, h3, l3;
                q2(v[w * 4 + 0], qa, inv, inv128, &h0, &l0);
                q2(v[w * 4 + 1], qa, inv, inv128, &h1, &l1);
                q2(v[w * 4 + 2], qa, inv, inv128, &h2, &l2);
                q2(v[w * 4 + 3], qa, inv, inv128, &h3, &l3);
                hw[w] = pack4(h0, h1, h2, h3);
                lw[w] = pack4(l0, l1, l2, l3);
            }
            Ah[ks] = (i32x4){hw[0], hw[1], hw[2], hw[3]};
            Al[ks] = (i32x4){lw[0], lw[1], lw[2], lw[3]};
        }
    }

    // int argmax state over S = 128*I1 + I2 + V (== argmin distance), 4 slots
    int b1[4], b2[4], bidx[4];
#pragma unroll
    for (int s = 0; s < 4; ++s) {
        b1[s] = -2147483647 - 1; b2[s] = -2147483647 - 1; bidx[s] = 0;
    }

    __syncthreads();   // full drain: chunk-0 + V stage + A loads visible

    for (int ch = 0; ch < NCHUNKS; ++ch) {
        const int buf = ch & 1;
        const int chbase = ch * NCH;
        // issue next chunk's stage FIRST, then counted wait on current's 4
        if (ch + 1 < NCHUNKS) {
            const signed char* sh = Bh_img + (size_t)(ch + 1) * (NCH * 128);
            const signed char* sl = Bl_img + (size_t)(ch + 1) * (NCH * 128);
#pragma unroll
            for (int i = 0; i < 2; ++i) {
                int e = (i * 256 + tid) * 16;
                gl_lds16(sh + e, &Bh[buf ^ 1][e]);
                gl_lds16(sl + e, &Bl[buf ^ 1][e]);
            }
            asm volatile("s_waitcnt vmcnt(4)" ::: "memory");
        } else {
            asm volatile("s_waitcnt vmcnt(0)" ::: "memory");
        }
        __builtin_amdgcn_s_barrier();

#pragma unroll
        for (int nt = 0; nt < 4; ++nt) {
            const int nl = nt * 16 + lr;
            const int v0 = Vs[chbase + nl];       // -c2/2 in I2-units
            i32x4 I1 = (i32x4){0, 0, 0, 0};
            i32x4 I2 = (i32x4){v0, v0, v0, v0};   // c2 folded into acc init: free
            __builtin_amdgcn_s_setprio(1);
#pragma unroll
            for (int ks = 0; ks < 2; ++ks) {
                const int e = nl * 128 + (((ks << 2) | q) ^ (lr & 7)) * 16;
                i32x4 bh = *(const i32x4*)(&Bh[buf][e]);
                i32x4 bl = *(const i32x4*)(&Bl[buf][e]);
                I1 = __builtin_amdgcn_mfma_i32_16x16x64_i8(Ah[ks], bh, I1, 0, 0, 0);
                I2 = __builtin_amdgcn_mfma_i32_16x16x64_i8(Ah[ks], bl, I2, 0, 0, 0);
                I2 = __builtin_amdgcn_mfma_i32_16x16x64_i8(Al[ks], bh, I2, 0, 0, 0);
            }
            __builtin_amdgcn_s_setprio(0);
            const int n_global = chbase + nl;
            // pure-int epilogue: 6 VALU/score
#pragma unroll
            for (int r = 0; r < 4; ++r) {
                int S = (int)(((u32)I1[r] << 7) + (u32)I2[r]);
                bool gt = S > b1[r];
                b2[r]   = max(b2[r], min(S, b1[r]));
                b1[r]   = max(S, b1[r]);
                bidx[r] = gt ? n_global : bidx[r];
            }
        }
        __builtin_amdgcn_s_barrier();   // all reads of buf done before restage
    }

    // butterfly over the 16 col-residue lanes (int max semantics, no tie-break:
    // ties -> gap 0 < margin -> exact refine resolves)
#pragma unroll
    for (int m = 1; m <= 8; m <<= 1) {
#pragma unroll
        for (int s = 0; s < 4; ++s) {
            int oa = __shfl_xor(b1[s], m, 64);
            int ob = __shfl_xor(b2[s], m, 64);
            int oi = __shfl_xor(bidx[s], m, 64);
            int mn = min(b1[s], oa);
            b2[s] = max(max(b2[s], ob), mn);
            bool take = oa > b1[s];
            b1[s]   = take ? oa : b1[s];
            bidx[s] = take ? oi : bidx[s];
        }
    }
    // slot s canonical in lane lr==s; row = wid*16 + q*4 + s
#pragma unroll
    for (int s = 0; s < 4; ++s) {
        if (lr == s) {
            int row = row_block + wid * 16 + q * 4 + s;
            out[row] = bidx[s];
            if (b1[s] - b2[s] < M_int) {
                int w = atomicAdd(counter, 1);
                if (w < WL_CAP) worklist[w] = row;
            }
        }
    }
}

// ---------------- fp64 refine (1024 threads, 2 coords/thread) ----------------

__global__ __launch_bounds__(1024) void refine_fp64(
        const float* __restrict__ latent, const float* __restrict__ coords,
        const int* __restrict__ worklist, const int* __restrict__ counter,
        int wl_cap, int* __restrict__ out) {
    __shared__ float  xs[D];
    __shared__ double rv[1024];
    __shared__ int    ri[1024];

    int n = *counter;
    if (n > wl_cap) n = wl_cap;

    for (int wi = blockIdx.x; wi < n; wi += gridDim.x) {
        int row = worklist[wi];
        if (threadIdx.x < D)
            xs[threadIdx.x] = latent[(size_t)row * D + threadIdx.x];
        __syncthreads();

        double best = 1.0e300;
        int    bix  = 0;
        for (int c = threadIdx.x; c < C; c += 1024) {
            const float4* cp = (const float4*)(coords + (size_t)c * D);
            double s0 = 0.0, s1 = 0.0, s2 = 0.0, s3 = 0.0;
#pragma unroll 8
            for (int k4 = 0; k4 < 32; ++k4) {
                float4 v = cp[k4];
                double d0 = (double)xs[k4 * 4 + 0] - (double)v.x;
                double d1 = (double)xs[k4 * 4 + 1] - (double)v.y;
                double d2 = (double)xs[k4 * 4 + 2] - (double)v.z;
                double d3 = (double)xs[k4 * 4 + 3] - (double)v.w;
                s0 = fma(d0, d0, s0); s1 = fma(d1, d1, s1);
                s2 = fma(d2, d2, s2); s3 = fma(d3, d3, s3);
            }
            double s = (s0 + s1) + (s2 + s3);
            if (s < best) { best = s; bix = c; }
        }
        rv[threadIdx.x] = best;
        ri[threadIdx.x] = bix;
        __syncthreads();
        for (int off = 512; off > 0; off >>= 1) {
            if (threadIdx.x < off) {
                double ov = rv[threadIdx.x + off];
                int    oi = ri[threadIdx.x + off];
                if (ov < rv[threadIdx.x] ||
                    (ov == rv[threadIdx.x] && oi < ri[threadIdx.x])) {
                    rv[threadIdx.x] = ov;
                    ri[threadIdx.x] = oi;
                }
            }
            __syncthreads();
        }
        if (threadIdx.x == 0) out[row] = ri[0];
        __syncthreads();
    }
}

extern "C" void kernel_launch(void* const* d_in, const int* in_sizes, int n_in,
                              void* d_out, int out_size, void* d_ws, size_t ws_size,
                              hipStream_t stream) {
    const float* latent = (const float*)d_in[0];
    const float* coords = (const float*)d_in[1];
    int*         out    = (int*)d_out;

    char* ws = (char*)d_ws;
    unsigned* amax  = (unsigned*)ws;
    int*    counter = (int*)(ws + WS_CNT);
    int*    wl      = (int*)(ws + WS_WL);
    int*    Vt      = (int*)(ws + WS_V);
    signed char* Bh = (signed char*)(ws + WS_BH);
    signed char* Bl = (signed char*)(ws + WS_BL);
    const int n_rows = in_sizes[0] / D;   // 131072
    const int nA4 = n_rows * D / 4;
    const int nB4 = C * D / 4;

    hipMemsetAsync(d_ws, 0, 16, stream);  // zero amax slots (stream-ordered)
    prep_amax<<<256, 256, 0, stream>>>(latent, nA4, coords, nB4, amax, counter);
    prep_coords<<<(C * 4) / 256, 256, 0, stream>>>(coords, amax, Bh, Bl, Vt);
    centroid_fast<<<n_rows / 64, 256, 0, stream>>>(latent, Bh, Bl, Vt, amax, out,
                                                   counter, wl);
    refine_fp64<<<608, 1024, 0, stream>>>(latent, coords, wl, counter, WL_CAP, out);
}

// Round 11
// 272.378 us; speedup vs baseline: 1.3593x; 1.0466x over previous
//
#include <hip/hip_runtime.h>

// Centroids: argmin_c ||latent[r] - coords[c]||^2, 131072 rows x 2048 coords, D=128.
//
// R11: attack the LDS-read amplification found in R10's accounting (every
//   resident wave reads the whole staged chunk: 16-row waves -> 32x amplification
//   = 82 us of LDS pipe > 52 us MFMA floor).
//   - 32-row waves (128 rows/block, grid 1024, launch_bounds(256,2): ~105 regs
//     fits the 128-VGPR slot -> still 4 waves/SIMD by the slot law
//     [waves/CU halve at 64/128/256]). LDS pipe 82 -> 41 us.
//   - NCH=32, dbuf LDS 16 KB -> 4 blocks/CU.
//   - per-WAVE qA (amax over the wave's 32 rows, shfl-only): latent never
//     pre-scanned -> prep_amax + memset dispatches DELETED (R10's +30 us).
//     v0 = rint(c2f_c * invqA_wave), c2f = -64*c2/qB precomputed; qB global
//     (redundant per-block coord scan in prep, coords = 1 MB).
//   - int argmax epilogue S = 128*I1 + I2 + v0 (R9/R10 validated), margin
//     M_int = 1.28/(qA_wave*qB) (= 0.01 half-scale units).
// Kept (validated): i8 hi/lo 3-pass mfma_i32_16x16x64_i8, gl_lds w=16 dbuf +
//   counted vmcnt(2), de-phase entry sleep, setprio(1) around MFMA,
//   no-tiebreak butterfly, fp64 refine margin net.
//
// ws layout (bytes): 0 qB (4B) | 16384 counter | 32768 worklist (128KB) |
//   196608 c2f (8KB float) | 262144 Bh (256KB) | 524288 Bl (256KB) | end 786432

constexpr int D = 128;
constexpr int C = 2048;
constexpr int NCH = 32;            // coords per chunk
constexpr int NCHUNKS = C / NCH;   // 64
constexpr int WL_CAP = 32768;

constexpr size_t WS_CNT = 16384;
constexpr size_t WS_WL  = 32768;
constexpr size_t WS_C2F = 196608;
constexpr size_t WS_BH  = 262144;
constexpr size_t WS_BL  = 524288;

typedef __attribute__((ext_vector_type(4))) int i32x4;
typedef unsigned int u32;

__device__ __forceinline__ int pack4(int a0, int a1, int a2, int a3) {
    return (int)(((u32)a0 & 255u) | (((u32)a1 & 255u) << 8) |
                 (((u32)a2 & 255u) << 16) | (((u32)a3 & 255u) << 24));
}

// quantize v -> hi (|h|<=127), lo (|l|<=64): v = h*qa + l*qa/128 + eps
__device__ __forceinline__ void q2(float v, float qa, float inv, float inv128,
                                   int* h, int* l) {
    float hf = __builtin_rintf(v * inv);
    *h = (int)hf;
    float r = fmaf(-hf, qa, v);
    *l = (int)__builtin_rintf(r * inv128);
}

// async global->LDS, 16B per lane (wave-uniform base + lane*16: contiguous).
__device__ __forceinline__ void gl_lds16(const void* g, void* l) {
    __builtin_amdgcn_global_load_lds(
        (const __attribute__((address_space(1))) u32*)g,
        (__attribute__((address_space(3))) u32*)l, 16, 0, 0);
}

// ---------------- prep: global qB + int8 B images + c2f ----------------
// 8 blocks x 1024 threads. Each block redundantly scans ALL coords (1 MB,
// L2-broadcast) for the global amax -> identical qB everywhere, no atomics,
// no pre-zeroed memory, no extra dispatch. Then thread t = (c, p=t&3)
// quantizes elems p*32..p*32+31 (granules g8 = 2p, 2p+1) at granule pos
// g8 ^ (c&7) (matches main-kernel read swizzle), and p==0 writes
// c2f[c] = -64*c2/qB.
__global__ __launch_bounds__(1024) void prep_coords(
        const float* __restrict__ coords,
        signed char* __restrict__ Bh,
        signed char* __restrict__ Bl,
        float* __restrict__ c2f, float* __restrict__ qBout,
        int* __restrict__ counter) {
    __shared__ float sW[16];
    int t = blockIdx.x * blockDim.x + threadIdx.x;
    if (t == 0) *counter = 0;

    // global amax over all coords (65536 float4 / 1024 threads = 64 each)
    float m = 0.f;
    for (int i = threadIdx.x; i < C * D / 4; i += 1024) {
        float4 v = ((const float4*)coords)[i];
        m = fmaxf(m, fmaxf(fmaxf(fabsf(v.x), fabsf(v.y)),
                           fmaxf(fabsf(v.z), fabsf(v.w))));
    }
#pragma unroll
    for (int s = 1; s <= 32; s <<= 1) m = fmaxf(m, __shfl_xor(m, s, 64));
    if ((threadIdx.x & 63) == 0) sW[threadIdx.x >> 6] = m;
    __syncthreads();
    float aB = 1e-30f;
#pragma unroll
    for (int i = 0; i < 16; ++i) aB = fmaxf(aB, sW[i]);

    float qb = aB * (1.f / 127.f);
    float inv = 127.f / aB;
    float inv128 = inv * 128.f;
    if (t == 0) *qBout = qb;

    int c = t >> 2, p = t & 3;
    float v[32];
#pragma unroll
    for (int i = 0; i < 8; ++i)
        *(float4*)(v + i * 4) = *(const float4*)(coords + (size_t)c * D + p * 32 + i * 4);
    float ss = 0.f;
#pragma unroll
    for (int j = 0; j < 32; ++j) ss = fmaf(v[j], v[j], ss);
#pragma unroll
    for (int s = 1; s <= 2; s <<= 1) ss += __shfl_xor(ss, s, 64);

#pragma unroll
    for (int g = 0; g < 2; ++g) {        // two 16-elem granules
        int g8 = p * 2 + g;
        int hw[4], lw[4];
#pragma unroll
        for (int w = 0; w < 4; ++w) {
            int h0, l0, h1, l1, h2, l2, h3, l3;
            q2(v[g * 16 + w * 4 + 0], qb, inv, inv128, &h0, &l0);
            q2(v[g * 16 + w * 4 + 1], qb, inv, inv128, &h1, &l1);
            q2(v[g * 16 + w * 4 + 2], qb, inv, inv128, &h2, &l2);
            q2(v[g * 16 + w * 4 + 3], qb, inv, inv128, &h3, &l3);
            hw[w] = pack4(h0, h1, h2, h3);
            lw[w] = pack4(l0, l1, l2, l3);
        }
        size_t off = (size_t)c * 128 + (size_t)((g8 ^ (c & 7)) * 16);
        *(i32x4*)(Bh + off) = (i32x4){hw[0], hw[1], hw[2], hw[3]};
        *(i32x4*)(Bl + off) = (i32x4){lw[0], lw[1], lw[2], lw[3]};
    }
    if (p == 0) c2f[c] = -64.f * ss / qb;
}

// ---------------- main kernel ----------------

__global__ __launch_bounds__(256, 2) void centroid_fast(
        const float* __restrict__ latent,
        const signed char* __restrict__ Bh_img,
        const signed char* __restrict__ Bl_img,
        const float* __restrict__ c2f,
        const float* __restrict__ qBp,
        int* __restrict__ out,
        int* __restrict__ counter,
        int* __restrict__ worklist) {
    // dbuf 2x4KB hi + 2x4KB lo = 16 KB -> 4 blocks/CU (128-VGPR slot, grid 4/CU)
    __shared__ __align__(16) signed char Bh[2][NCH * 128], Bl[2][NCH * 128];

    const int tid  = threadIdx.x;
    const int wid  = tid >> 6;            // wave 0..3 -> rows wid*32..wid*32+31
    const int lane = tid & 63;
    const int q    = lane >> 4, lr = lane & 15;
    const int row_block = blockIdx.x * 128;

    // de-phase co-resident blocks (validated R3): 4 phases
    {
        int ph = (blockIdx.x ^ (blockIdx.x >> 8)) & 3;
        for (int i = 0; i < ph * 2; ++i) __builtin_amdgcn_s_sleep(8);
    }

    // ---- prologue: stage chunk 0 (2 gl_lds: 4KB per image = 256 thr x 16B) ----
    gl_lds16(Bh_img + tid * 16, &Bh[0][tid * 16]);
    gl_lds16(Bl_img + tid * 16, &Bl[0][tid * 16]);

    const float qB = *qBp;

    // ---- A fragments: int8 hi/lo with per-WAVE qA (amax over the wave's 32
    // rows; shfl-only, no barrier). Lane holds rows wid*32 + mt*16 + lr,
    // k = ks*64 + q*16 + 0..15 -> i32x4 per (mt,ks). 32 VGPRs long-lived.
    i32x4 Ah[2][2], Al[2][2];
    float invqA, qa;
    {
        float v[2][32];
#pragma unroll
        for (int mt = 0; mt < 2; ++mt) {
            const float* rp = latent + (size_t)(row_block + wid * 32 + mt * 16 + lr) * D;
#pragma unroll
            for (int ks = 0; ks < 2; ++ks)
#pragma unroll
                for (int i = 0; i < 4; ++i)
                    *(float4*)(v[mt] + ks * 16 + i * 4) =
                        *(const float4*)(rp + ks * 64 + q * 16 + i * 4);
        }
        float amax = 0.f;
#pragma unroll
        for (int mt = 0; mt < 2; ++mt)
#pragma unroll
            for (int j = 0; j < 32; ++j) amax = fmaxf(amax, fabsf(v[mt][j]));
#pragma unroll
        for (int s = 1; s <= 32; s <<= 1) amax = fmaxf(amax, __shfl_xor(amax, s, 64));
        amax = fmaxf(amax, 1e-30f);
        qa = amax * (1.f / 127.f);
        invqA = 1.f / qa;
        float inv = 127.f / amax;
        float inv128 = inv * 128.f;
#pragma unroll
        for (int mt = 0; mt < 2; ++mt)
#pragma unroll
            for (int ks = 0; ks < 2; ++ks) {
                int hw[4], lw[4];
#pragma unroll
                for (int w = 0; w < 4; ++w) {
                    int h0, l0, h1, l1, h2, l2, h3, l3;
                    q2(v[mt][ks * 16 + w * 4 + 0], qa, inv, inv128, &h0, &l0);
                    q2(v[mt][ks * 16 + w * 4 + 1], qa, inv, inv128, &h1, &l1);
                    q2(v[mt][ks * 16 + w * 4 + 2], qa, inv, inv128, &h2, &l2);
                    q2(v[mt][ks * 16 + w * 4 + 3], qa, inv, inv128, &h3, &l3);
                    hw[w] = pack4(h0, h1, h2, h3);
                    lw[w] = pack4(l0, l1, l2, l3);
                }
                Ah[mt][ks] = (i32x4){hw[0], hw[1], hw[2], hw[3]};
                Al[mt][ks] = (i32x4){lw[0], lw[1], lw[2], lw[3]};
            }
    }
    const int M_int = (int)(1.28f / (qa * qB)) + 1;   // margin 0.01 half-scale

    // int argmax state over S = 128*I1 + I2 + v0 (== argmin distance), 8 slots
    int b1[8], b2[8], bidx[8];
#pragma unroll
    for (int s = 0; s < 8; ++s) {
        b1[s] = -2147483647 - 1; b2[s] = -2147483647 - 1; bidx[s] = 0;
    }

    __syncthreads();   // full drain: chunk-0 stage + A loads visible

    for (int ch = 0; ch < NCHUNKS; ++ch) {
        const int buf = ch & 1;
        const int chbase = ch * NCH;
        // issue next chunk's stage FIRST, then counted wait on current's 2
        if (ch + 1 < NCHUNKS) {
            const signed char* sh = Bh_img + (size_t)(ch + 1) * (NCH * 128);
            const signed char* sl = Bl_img + (size_t)(ch + 1) * (NCH * 128);
            gl_lds16(sh + tid * 16, &Bh[buf ^ 1][tid * 16]);
            gl_lds16(sl + tid * 16, &Bl[buf ^ 1][tid * 16]);
            asm volatile("s_waitcnt vmcnt(2)" ::: "memory");
        } else {
            asm volatile("s_waitcnt vmcnt(0)" ::: "memory");
        }
        __builtin_amdgcn_s_barrier();

        // per-chunk c2f (L2-resident 8KB table; issued here, consumed in the
        // epilogues -> drained before next iteration's counted vmcnt)
        float cf[2];
        cf[0] = c2f[chbase + lr];
        cf[1] = c2f[chbase + 16 + lr];

#pragma unroll
        for (int nt = 0; nt < 2; ++nt) {
            const int nl = nt * 16 + lr;
            const int v0 = (int)__builtin_rintf(cf[nt] * invqA);
            i32x4 I1[2], I2[2];
#pragma unroll
            for (int mt = 0; mt < 2; ++mt) {
                I1[mt] = (i32x4){0, 0, 0, 0};
                I2[mt] = (i32x4){v0, v0, v0, v0};   // c2 folded into acc init
            }
            __builtin_amdgcn_s_setprio(1);
#pragma unroll
            for (int ks = 0; ks < 2; ++ks) {
                const int e = nl * 128 + (((ks << 2) | q) ^ (lr & 7)) * 16;
                i32x4 bh = *(const i32x4*)(&Bh[buf][e]);
                i32x4 bl = *(const i32x4*)(&Bl[buf][e]);
#pragma unroll
                for (int mt = 0; mt < 2; ++mt)
                    I1[mt] = __builtin_amdgcn_mfma_i32_16x16x64_i8(Ah[mt][ks], bh, I1[mt], 0, 0, 0);
#pragma unroll
                for (int mt = 0; mt < 2; ++mt)
                    I2[mt] = __builtin_amdgcn_mfma_i32_16x16x64_i8(Ah[mt][ks], bl, I2[mt], 0, 0, 0);
#pragma unroll
                for (int mt = 0; mt < 2; ++mt)
                    I2[mt] = __builtin_amdgcn_mfma_i32_16x16x64_i8(Al[mt][ks], bh, I2[mt], 0, 0, 0);
            }
            __builtin_amdgcn_s_setprio(0);
            const int n_global = chbase + nl;
            // pure-int epilogue: 6 VALU/score
#pragma unroll
            for (int mt = 0; mt < 2; ++mt)
#pragma unroll
                for (int r = 0; r < 4; ++r) {
                    int slot = mt * 4 + r;
                    int S = (int)(((u32)I1[mt][r] << 7) + (u32)I2[mt][r]);
                    bool gt  = S > b1[slot];
                    b2[slot]   = max(b2[slot], min(S, b1[slot]));
                    b1[slot]   = max(S, b1[slot]);
                    bidx[slot] = gt ? n_global : bidx[slot];
                }
        }
        __builtin_amdgcn_s_barrier();   // all reads of buf done before restage
    }

    // butterfly over the 16 col-residue lanes (int max semantics, no tie-break:
    // ties -> gap 0 < margin -> exact refine resolves)
#pragma unroll
    for (int m = 1; m <= 8; m <<= 1) {
#pragma unroll
        for (int s = 0; s < 8; ++s) {
            int oa = __shfl_xor(b1[s], m, 64);
            int ob = __shfl_xor(b2[s], m, 64);
            int oi = __shfl_xor(bidx[s], m, 64);
            int mn = min(b1[s], oa);
            b2[s] = max(max(b2[s], ob), mn);
            bool take = oa > b1[s];
            b1[s]   = take ? oa : b1[s];
            bidx[s] = take ? oi : bidx[s];
        }
    }
    // slot s canonical in lane lr==s; row = wid*32 + (s>>2)*16 + q*4 + (s&3)
#pragma unroll
    for (int s = 0; s < 8; ++s) {
        if (lr == s) {
            int row = row_block + wid * 32 + (s >> 2) * 16 + q * 4 + (s & 3);
            out[row] = bidx[s];
            if (b1[s] - b2[s] < M_int) {
                int w = atomicAdd(counter, 1);
                if (w < WL_CAP) worklist[w] = row;
            }
        }
    }
}

// ---------------- fp64 refine (1024 threads, 2 coords/thread) ----------------

__global__ __launch_bounds__(1024) void refine_fp64(
        const float* __restrict__ latent, const float* __restrict__ coords,
        const int* __restrict__ worklist, const int* __restrict__ counter,
        int wl_cap, int* __restrict__ out) {
    __shared__ float  xs[D];
    __shared__ double rv[1024];
    __shared__ int    ri[1024];

    int n = *counter;
    if (n > wl_cap) n = wl_cap;

    for (int wi = blockIdx.x; wi < n; wi += gridDim.x) {
        int row = worklist[wi];
        if (threadIdx.x < D)
            xs[threadIdx.x] = latent[(size_t)row * D + threadIdx.x];
        __syncthreads();

        double best = 1.0e300;
        int    bix  = 0;
        for (int c = threadIdx.x; c < C; c += 1024) {
            const float4* cp = (const float4*)(coords + (size_t)c * D);
            double s0 = 0.0, s1 = 0.0, s2 = 0.0, s3 = 0.0;
#pragma unroll 8
            for (int k4 = 0; k4 < 32; ++k4) {
                float4 v = cp[k4];
                double d0 = (double)xs[k4 * 4 + 0] - (double)v.x;
                double d1 = (double)xs[k4 * 4 + 1] - (double)v.y;
                double d2 = (double)xs[k4 * 4 + 2] - (double)v.z;
                double d3 = (double)xs[k4 * 4 + 3] - (double)v.w;
                s0 = fma(d0, d0, s0); s1 = fma(d1, d1, s1);
                s2 = fma(d2, d2, s2); s3 = fma(d3, d3, s3);
            }
            double s = (s0 + s1) + (s2 + s3);
            if (s < best) { best = s; bix = c; }
        }
        rv[threadIdx.x] = best;
        ri[threadIdx.x] = bix;
        __syncthreads();
        for (int off = 512; off > 0; off >>= 1) {
            if (threadIdx.x < off) {
                double ov = rv[threadIdx.x + off];
                int    oi = ri[threadIdx.x + off];
                if (ov < rv[threadIdx.x] ||
                    (ov == rv[threadIdx.x] && oi < ri[threadIdx.x])) {
                    rv[threadIdx.x] = ov;
                    ri[threadIdx.x] = oi;
                }
            }
            __syncthreads();
        }
        if (threadIdx.x == 0) out[row] = ri[0];
        __syncthreads();
    }
}

extern "C" void kernel_launch(void* const* d_in, const int* in_sizes, int n_in,
                              void* d_out, int out_size, void* d_ws, size_t ws_size,
                              hipStream_t stream) {
    const float* latent = (const float*)d_in[0];
    const float* coords = (const float*)d_in[1];
    int*         out    = (int*)d_out;

    char* ws = (char*)d_ws;
    float*  qB      = (float*)ws;
    int*    counter = (int*)(ws + WS_CNT);
    int*    wl      = (int*)(ws + WS_WL);
    float*  c2f     = (float*)(ws + WS_C2F);
    signed char* Bh = (signed char*)(ws + WS_BH);
    signed char* Bl = (signed char*)(ws + WS_BL);
    const int n_rows = in_sizes[0] / D;   // 131072

    prep_coords<<<8, 1024, 0, stream>>>(coords, Bh, Bl, c2f, qB, counter);
    centroid_fast<<<n_rows / 128, 256, 0, stream>>>(latent, Bh, Bl, c2f, qB, out,
                                                    counter, wl);
    refine_fp64<<<608, 1024, 0, stream>>>(latent, coords, wl, counter, WL_CAP, out);
}

// Round 12
// 271.057 us; speedup vs baseline: 1.3659x; 1.0049x over previous
//
#include <hip/hip_runtime.h>

// Centroids: argmin_c ||latent[r] - coords[c]||^2, 131072 rows x 2048 coords, D=128.
//
// R12: amortize the per-chunk serial region (R11 analysis: pipes only ~33%
//   utilized -> bubble-bound; VALUBusy includes MFMA issue, true VALU ~20%).
//   - NCH=64 (32 chunks): barrier count halves vs R11; per-chunk fixed costs
//     (vmcnt wait, cf loads, prime ds_read) amortized over 48 MFMA/wave.
//     LDS-read traffic is NCH-invariant (set by rows/wave=32, R10 lesson).
//   - one-step B-fragment ds_read prefetch (+8 VGPR): prime latency once per
//     chunk, not per ks-group. Budget ~84 of 128 (R2's spill was 140/128;
//     grid=1024 caps at 4 waves/SIMD so VGPR<=128 is free).
// Kept (validated R9-R11): per-WAVE qA (no latent pre-scan, 3 dispatches),
//   global qB via redundant block scan in prep, int argmax S = 128*I1+I2+v0
//   with v0 = rint(c2f*invqA) folded into I2 acc-init, i8 hi/lo 3-pass
//   mfma_i32_16x16x64_i8, gl_lds w=16 dbuf + counted vmcnt(4), de-phase sleep,
//   setprio(1) around MFMA, no-tiebreak butterfly, fp64 refine margin net
//   (M_int = 1.28/(qA*qB) == 0.01 half-scale, ~7 sigma).
//
// ws layout (bytes): 0 qB (4B) | 16384 counter | 32768 worklist (128KB) |
//   196608 c2f (8KB float) | 262144 Bh (256KB) | 524288 Bl (256KB) | end 786432

constexpr int D = 128;
constexpr int C = 2048;
constexpr int NCH = 64;            // coords per chunk
constexpr int NCHUNKS = C / NCH;   // 32
constexpr int WL_CAP = 32768;

constexpr size_t WS_CNT = 16384;
constexpr size_t WS_WL  = 32768;
constexpr size_t WS_C2F = 196608;
constexpr size_t WS_BH  = 262144;
constexpr size_t WS_BL  = 524288;

typedef __attribute__((ext_vector_type(4))) int i32x4;
typedef unsigned int u32;

__device__ __forceinline__ int pack4(int a0, int a1, int a2, int a3) {
    return (int)(((u32)a0 & 255u) | (((u32)a1 & 255u) << 8) |
                 (((u32)a2 & 255u) << 16) | (((u32)a3 & 255u) << 24));
}

// quantize v -> hi (|h|<=127), lo (|l|<=64): v = h*qa + l*qa/128 + eps
__device__ __forceinline__ void q2(float v, float qa, float inv, float inv128,
                                   int* h, int* l) {
    float hf = __builtin_rintf(v * inv);
    *h = (int)hf;
    float r = fmaf(-hf, qa, v);
    *l = (int)__builtin_rintf(r * inv128);
}

// async global->LDS, 16B per lane (wave-uniform base + lane*16: contiguous).
__device__ __forceinline__ void gl_lds16(const void* g, void* l) {
    __builtin_amdgcn_global_load_lds(
        (const __attribute__((address_space(1))) u32*)g,
        (__attribute__((address_space(3))) u32*)l, 16, 0, 0);
}

// ---------------- prep: global qB + int8 B images + c2f ----------------
// 8 blocks x 1024 threads. Each block redundantly scans ALL coords (1 MB,
// L2-broadcast) for the global amax -> identical qB everywhere, no atomics.
// Thread t = (c, p=t&3) quantizes elems p*32..p*32+31 (granules g8 = 2p,2p+1)
// at granule pos g8 ^ (c&7); p==0 writes c2f[c] = -64*c2/qB.
__global__ __launch_bounds__(1024) void prep_coords(
        const float* __restrict__ coords,
        signed char* __restrict__ Bh,
        signed char* __restrict__ Bl,
        float* __restrict__ c2f, float* __restrict__ qBout,
        int* __restrict__ counter) {
    __shared__ float sW[16];
    int t = blockIdx.x * blockDim.x + threadIdx.x;
    if (t == 0) *counter = 0;

    // global amax over all coords (65536 float4 / 1024 threads = 64 each)
    float m = 0.f;
    for (int i = threadIdx.x; i < C * D / 4; i += 1024) {
        float4 v = ((const float4*)coords)[i];
        m = fmaxf(m, fmaxf(fmaxf(fabsf(v.x), fabsf(v.y)),
                           fmaxf(fabsf(v.z), fabsf(v.w))));
    }
#pragma unroll
    for (int s = 1; s <= 32; s <<= 1) m = fmaxf(m, __shfl_xor(m, s, 64));
    if ((threadIdx.x & 63) == 0) sW[threadIdx.x >> 6] = m;
    __syncthreads();
    float aB = 1e-30f;
#pragma unroll
    for (int i = 0; i < 16; ++i) aB = fmaxf(aB, sW[i]);

    float qb = aB * (1.f / 127.f);
    float inv = 127.f / aB;
    float inv128 = inv * 128.f;
    if (t == 0) *qBout = qb;

    int c = t >> 2, p = t & 3;
    float v[32];
#pragma unroll
    for (int i = 0; i < 8; ++i)
        *(float4*)(v + i * 4) = *(const float4*)(coords + (size_t)c * D + p * 32 + i * 4);
    float ss = 0.f;
#pragma unroll
    for (int j = 0; j < 32; ++j) ss = fmaf(v[j], v[j], ss);
#pragma unroll
    for (int s = 1; s <= 2; s <<= 1) ss += __shfl_xor(ss, s, 64);

#pragma unroll
    for (int g = 0; g < 2; ++g) {        // two 16-elem granules
        int g8 = p * 2 + g;
        int hw[4], lw[4];
#pragma unroll
        for (int w = 0; w < 4; ++w) {
            int h0, l0, h1, l1, h2, l2, h3, l3;
            q2(v[g * 16 + w * 4 + 0], qb, inv, inv128, &h0, &l0);
            q2(v[g * 16 + w * 4 + 1], qb, inv, inv128, &h1, &l1);
            q2(v[g * 16 + w * 4 + 2], qb, inv, inv128, &h2, &l2);
            q2(v[g * 16 + w * 4 + 3], qb, inv, inv128, &h3, &l3);
            hw[w] = pack4(h0, h1, h2, h3);
            lw[w] = pack4(l0, l1, l2, l3);
        }
        size_t off = (size_t)c * 128 + (size_t)((g8 ^ (c & 7)) * 16);
        *(i32x4*)(Bh + off) = (i32x4){hw[0], hw[1], hw[2], hw[3]};
        *(i32x4*)(Bl + off) = (i32x4){lw[0], lw[1], lw[2], lw[3]};
    }
    if (p == 0) c2f[c] = -64.f * ss / qb;
}

// ---------------- main kernel ----------------

__global__ __launch_bounds__(256, 2) void centroid_fast(
        const float* __restrict__ latent,
        const signed char* __restrict__ Bh_img,
        const signed char* __restrict__ Bl_img,
        const float* __restrict__ c2f,
        const float* __restrict__ qBp,
        int* __restrict__ out,
        int* __restrict__ counter,
        int* __restrict__ worklist) {
    // dbuf 2x8KB hi + 2x8KB lo = 32 KB -> 4 blocks/CU (grid 1024 = 4/CU)
    __shared__ __align__(16) signed char Bh[2][NCH * 128], Bl[2][NCH * 128];

    const int tid  = threadIdx.x;
    const int wid  = tid >> 6;            // wave 0..3 -> rows wid*32..wid*32+31
    const int lane = tid & 63;
    const int q    = lane >> 4, lr = lane & 15;
    const int row_block = blockIdx.x * 128;

    // de-phase co-resident blocks (validated R3): 4 phases
    {
        int ph = (blockIdx.x ^ (blockIdx.x >> 8)) & 3;
        for (int i = 0; i < ph * 2; ++i) __builtin_amdgcn_s_sleep(8);
    }

    // ---- prologue: stage chunk 0 (4 gl_lds: 8KB/image = 2 x 256thr x 16B) ----
#pragma unroll
    for (int i = 0; i < 2; ++i) {
        int e = (i * 256 + tid) * 16;
        gl_lds16(Bh_img + e, &Bh[0][e]);
        gl_lds16(Bl_img + e, &Bl[0][e]);
    }

    const float qB = *qBp;

    // ---- A fragments: int8 hi/lo with per-WAVE qA (amax over the wave's 32
    // rows; shfl-only, no barrier). Lane holds rows wid*32 + mt*16 + lr,
    // k = ks*64 + q*16 + 0..15 -> i32x4 per (mt,ks). 32 VGPRs long-lived.
    i32x4 Ah[2][2], Al[2][2];
    float invqA, qa;
    {
        float v[2][32];
#pragma unroll
        for (int mt = 0; mt < 2; ++mt) {
            const float* rp = latent + (size_t)(row_block + wid * 32 + mt * 16 + lr) * D;
#pragma unroll
            for (int ks = 0; ks < 2; ++ks)
#pragma unroll
                for (int i = 0; i < 4; ++i)
                    *(float4*)(v[mt] + ks * 16 + i * 4) =
                        *(const float4*)(rp + ks * 64 + q * 16 + i * 4);
        }
        float amax = 0.f;
#pragma unroll
        for (int mt = 0; mt < 2; ++mt)
#pragma unroll
            for (int j = 0; j < 32; ++j) amax = fmaxf(amax, fabsf(v[mt][j]));
#pragma unroll
        for (int s = 1; s <= 32; s <<= 1) amax = fmaxf(amax, __shfl_xor(amax, s, 64));
        amax = fmaxf(amax, 1e-30f);
        qa = amax * (1.f / 127.f);
        invqA = 1.f / qa;
        float inv = 127.f / amax;
        float inv128 = inv * 128.f;
#pragma unroll
        for (int mt = 0; mt < 2; ++mt)
#pragma unroll
            for (int ks = 0; ks < 2; ++ks) {
                int hw[4], lw[4];
#pragma unroll
                for (int w = 0; w < 4; ++w) {
                    int h0, l0, h1, l1, h2, l2, h3, l3;
                    q2(v[mt][ks * 16 + w * 4 + 0], qa, inv, inv128, &h0, &l0);
                    q2(v[mt][ks * 16 + w * 4 + 1], qa, inv, inv128, &h1, &l1);
                    q2(v[mt][ks * 16 + w * 4 + 2], qa, inv, inv128, &h2, &l2);
                    q2(v[mt][ks * 16 + w * 4 + 3], qa, inv, inv128, &h3, &l3);
                    hw[w] = pack4(h0, h1, h2, h3);
                    lw[w] = pack4(l0, l1, l2, l3);
                }
                Ah[mt][ks] = (i32x4){hw[0], hw[1], hw[2], hw[3]};
                Al[mt][ks] = (i32x4){lw[0], lw[1], lw[2], lw[3]};
            }
    }
    const int M_int = (int)(1.28f / (qa * qB)) + 1;   // margin 0.01 half-scale

    // int argmax state over S = 128*I1 + I2 + v0 (== argmin distance), 8 slots
    int b1[8], b2[8], bidx[8];
#pragma unroll
    for (int s = 0; s < 8; ++s) {
        b1[s] = -2147483647 - 1; b2[s] = -2147483647 - 1; bidx[s] = 0;
    }

    __syncthreads();   // full drain: chunk-0 stage + A loads visible

    for (int ch = 0; ch < NCHUNKS; ++ch) {
        const int buf = ch & 1;
        const int chbase = ch * NCH;
        // issue next chunk's stage FIRST, then counted wait on current's 4
        if (ch + 1 < NCHUNKS) {
            const signed char* sh = Bh_img + (size_t)(ch + 1) * (NCH * 128);
            const signed char* sl = Bl_img + (size_t)(ch + 1) * (NCH * 128);
#pragma unroll
            for (int i = 0; i < 2; ++i) {
                int e = (i * 256 + tid) * 16;
                gl_lds16(sh + e, &Bh[buf ^ 1][e]);
                gl_lds16(sl + e, &Bl[buf ^ 1][e]);
            }
            asm volatile("s_waitcnt vmcnt(4)" ::: "memory");
        } else {
            asm volatile("s_waitcnt vmcnt(0)" ::: "memory");
        }
        __builtin_amdgcn_s_barrier();

        // per-chunk c2f (L2-resident 8KB; consumed at each nt -> drained
        // before next iteration's counted vmcnt)
        float cf[4];
#pragma unroll
        for (int nt = 0; nt < 4; ++nt) cf[nt] = c2f[chbase + nt * 16 + lr];

        // prime (nt=0, ks=0) B fragments
        i32x4 bh = *(const i32x4*)(&Bh[buf][lr * 128 + (q ^ (lr & 7)) * 16]);
        i32x4 bl = *(const i32x4*)(&Bl[buf][lr * 128 + (q ^ (lr & 7)) * 16]);

#pragma unroll
        for (int nt = 0; nt < 4; ++nt) {
            const int nl = nt * 16 + lr;
            const int v0 = (int)__builtin_rintf(cf[nt] * invqA);
            i32x4 I1[2], I2[2];
#pragma unroll
            for (int mt = 0; mt < 2; ++mt) {
                I1[mt] = (i32x4){0, 0, 0, 0};
                I2[mt] = (i32x4){v0, v0, v0, v0};   // c2 folded into acc init
            }
            __builtin_amdgcn_s_setprio(1);
#pragma unroll
            for (int ks = 0; ks < 2; ++ks) {
                // prefetch next fragment (one step ahead) before the MFMAs
                i32x4 nbh, nbl;
                if (ks == 0) {
                    const int e = nl * 128 + (((1 << 2) | q) ^ (lr & 7)) * 16;
                    nbh = *(const i32x4*)(&Bh[buf][e]);
                    nbl = *(const i32x4*)(&Bl[buf][e]);
                } else if (nt < 3) {
                    const int e = (nl + 16) * 128 + (q ^ (lr & 7)) * 16;
                    nbh = *(const i32x4*)(&Bh[buf][e]);
                    nbl = *(const i32x4*)(&Bl[buf][e]);
                }
#pragma unroll
                for (int mt = 0; mt < 2; ++mt)
                    I1[mt] = __builtin_amdgcn_mfma_i32_16x16x64_i8(Ah[mt][ks], bh, I1[mt], 0, 0, 0);
#pragma unroll
                for (int mt = 0; mt < 2; ++mt)
                    I2[mt] = __builtin_amdgcn_mfma_i32_16x16x64_i8(Ah[mt][ks], bl, I2[mt], 0, 0, 0);
#pragma unroll
                for (int mt = 0; mt < 2; ++mt)
                    I2[mt] = __builtin_amdgcn_mfma_i32_16x16x64_i8(Al[mt][ks], bh, I2[mt], 0, 0, 0);
                if (ks == 0 || nt < 3) { bh = nbh; bl = nbl; }
            }
            __builtin_amdgcn_s_setprio(0);
            const int n_global = chbase + nl;
            // pure-int epilogue: 6 VALU/score
#pragma unroll
            for (int mt = 0; mt < 2; ++mt)
#pragma unroll
                for (int r = 0; r < 4; ++r) {
                    int slot = mt * 4 + r;
                    int S = (int)(((u32)I1[mt][r] << 7) + (u32)I2[mt][r]);
                    bool gt  = S > b1[slot];
                    b2[slot]   = max(b2[slot], min(S, b1[slot]));
                    b1[slot]   = max(S, b1[slot]);
                    bidx[slot] = gt ? n_global : bidx[slot];
                }
        }
        __builtin_amdgcn_s_barrier();   // all reads of buf done before restage
    }

    // butterfly over the 16 col-residue lanes (int max semantics, no tie-break:
    // ties -> gap 0 < margin -> exact refine resolves)
#pragma unroll
    for (int m = 1; m <= 8; m <<= 1) {
#pragma unroll
        for (int s = 0; s < 8; ++s) {
            int oa = __shfl_xor(b1[s], m, 64);
            int ob = __shfl_xor(b2[s], m, 64);
            int oi = __shfl_xor(bidx[s], m, 64);
            int mn = min(b1[s], oa);
            b2[s] = max(max(b2[s], ob), mn);
            bool take = oa > b1[s];
            b1[s]   = take ? oa : b1[s];
            bidx[s] = take ? oi : bidx[s];
        }
    }
    // slot s canonical in lane lr==s; row = wid*32 + (s>>2)*16 + q*4 + (s&3)
#pragma unroll
    for (int s = 0; s < 8; ++s) {
        if (lr == s) {
            int row = row_block + wid * 32 + (s >> 2) * 16 + q * 4 + (s & 3);
            out[row] = bidx[s];
            if (b1[s] - b2[s] < M_int) {
                int w = atomicAdd(counter, 1);
                if (w < WL_CAP) worklist[w] = row;
            }
        }
    }
}

// ---------------- fp64 refine (1024 threads, 2 coords/thread) ----------------

__global__ __launch_bounds__(1024) void refine_fp64(
        const float* __restrict__ latent, const float* __restrict__ coords,
        const int* __restrict__ worklist, const int* __restrict__ counter,
        int wl_cap, int* __restrict__ out) {
    __shared__ float  xs[D];
    __shared__ double rv[1024];
    __shared__ int    ri[1024];

    int n = *counter;
    if (n > wl_cap) n = wl_cap;

    for (int wi = blockIdx.x; wi < n; wi += gridDim.x) {
        int row = worklist[wi];
        if (threadIdx.x < D)
            xs[threadIdx.x] = latent[(size_t)row * D + threadIdx.x];
        __syncthreads();

        double best = 1.0e300;
        int    bix  = 0;
        for (int c = threadIdx.x; c < C; c += 1024) {
            const float4* cp = (const float4*)(coords + (size_t)c * D);
            double s0 = 0.0, s1 = 0.0, s2 = 0.0, s3 = 0.0;
#pragma unroll 8
            for (int k4 = 0; k4 < 32; ++k4) {
                float4 v = cp[k4];
                double d0 = (double)xs[k4 * 4 + 0] - (double)v.x;
                double d1 = (double)xs[k4 * 4 + 1] - (double)v.y;
                double d2 = (double)xs[k4 * 4 + 2] - (double)v.z;
                double d3 = (double)xs[k4 * 4 + 3] - (double)v.w;
                s0 = fma(d0, d0, s0); s1 = fma(d1, d1, s1);
                s2 = fma(d2, d2, s2); s3 = fma(d3, d3, s3);
            }
            double s = (s0 + s1) + (s2 + s3);
            if (s < best) { best = s; bix = c; }
        }
        rv[threadIdx.x] = best;
        ri[threadIdx.x] = bix;
        __syncthreads();
        for (int off = 512; off > 0; off >>= 1) {
            if (threadIdx.x < off) {
                double ov = rv[threadIdx.x + off];
                int    oi = ri[threadIdx.x + off];
                if (ov < rv[threadIdx.x] ||
                    (ov == rv[threadIdx.x] && oi < ri[threadIdx.x])) {
                    rv[threadIdx.x] = ov;
                    ri[threadIdx.x] = oi;
                }
            }
            __syncthreads();
        }
        if (threadIdx.x == 0) out[row] = ri[0];
        __syncthreads();
    }
}

extern "C" void kernel_launch(void* const* d_in, const int* in_sizes, int n_in,
                              void* d_out, int out_size, void* d_ws, size_t ws_size,
                              hipStream_t stream) {
    const float* latent = (const float*)d_in[0];
    const float* coords = (const float*)d_in[1];
    int*         out    = (int*)d_out;

    char* ws = (char*)d_ws;
    float*  qB      = (float*)ws;
    int*    counter = (int*)(ws + WS_CNT);
    int*    wl      = (int*)(ws + WS_WL);
    float*  c2f     = (float*)(ws + WS_C2F);
    signed char* Bh = (signed char*)(ws + WS_BH);
    signed char* Bl = (signed char*)(ws + WS_BL);
    const int n_rows = in_sizes[0] / D;   // 131072

    prep_coords<<<8, 1024, 0, stream>>>(coords, Bh, Bl, c2f, qB, counter);
    centroid_fast<<<n_rows / 128, 256, 0, stream>>>(latent, Bh, Bl, c2f, qB, out,
                                                    counter, wl);
    refine_fp64<<<608, 1024, 0, stream>>>(latent, coords, wl, counter, WL_CAP, out);
}